// Round 4
// baseline (199.360 us; speedup 1.0000x reference)
//
#include <hip/hip_runtime.h>

// Round 4: occupancy attack. attn inner loop unchanged (verified), but
// k-split=2 across blocks (additive partials thanks to no-max softmax),
// grid 512 = 2 blocks/CU. proj rebuilt: 8 waves (2/SIMD), within-block
// K-split, all waves compute (2 QK tiles transposed + 1 V tile direct).

typedef __bf16 bf16;
typedef __bf16 bf16x4 __attribute__((ext_vector_type(4)));
typedef __bf16 bf16x8 __attribute__((ext_vector_type(8)));
typedef float  f32x16 __attribute__((ext_vector_type(16)));

#define MFMA(a, b, c) __builtin_amdgcn_mfma_f32_32x32x16_bf16(a, b, c, 0, 0, 0)

constexpr int T = 4096, D = 1024, HS = 64;
constexpr int ROWS = 4 * T;                   // 16384
constexpr float QSCL = 0.045084220027797f;    // (1/32) * log2(e)

__device__ inline f32x16 zero16() {
    f32x16 z;
#pragma unroll
    for (int i = 0; i < 16; ++i) z[i] = 0.f;
    return z;
}

// ---- prep: Wt[192][1024] bf16 = concat(Wq^T*QSCL, Wk^T, Wv^T) ----
__global__ __launch_bounds__(256) void prep_wt(
    const float* __restrict__ Wq, const float* __restrict__ Wk,
    const float* __restrict__ Wv, bf16* __restrict__ Wt)
{
    __shared__ float Xf[64 * 68];
    const int m = blockIdx.x >> 4, dt = blockIdx.x & 15;
    const float* W = (m == 0) ? Wq : ((m == 1) ? Wk : Wv);
    const int d0 = dt * 64;
#pragma unroll
    for (int j = 0; j < 4; ++j) {
        int i = threadIdx.x + 256 * j;
        int dr = i >> 4, c4 = i & 15;
        float4 v = *(const float4*)(W + (size_t)(d0 + dr) * 64 + c4 * 4);
        *(float4*)&Xf[dr * 68 + c4 * 4] = v;
    }
    __syncthreads();
    const float scl = (m == 0) ? QSCL : 1.0f;
#pragma unroll
    for (int j = 0; j < 4; ++j) {
        int o = threadIdx.x + 256 * j;
        int h = o >> 4, dc = o & 15;
        bf16x4 w;
#pragma unroll
        for (int k = 0; k < 4; ++k) w[k] = (bf16)(Xf[(dc * 4 + k) * 68 + h] * scl);
        *(bf16x4*)(Wt + (size_t)(m * 64 + h) * D + d0 + dc * 4) = w;
    }
}

// ---- projection: 512 thr / 8 waves, M-tile 64, within-block K-split ----
// Wave (s = K-half, wn): QK tiles (h-pair hp=wn>>1, t-tile tt=wn&1) via
// C^T = Wt*Xs^T; V tile (t-row tt, h-col hp) via C = Xs*Wt^T. The Xs
// fragment serves as B (QK) and A (V) with identical register content.
__global__ __launch_bounds__(512, 1) void qkv_proj(
    const float* __restrict__ x, const bf16* __restrict__ Wt,
    bf16* __restrict__ Qg, bf16* __restrict__ Kg, bf16* __restrict__ Vtg)
{
    __shared__ __align__(16) short Xs[2][64 * 72];   // [K-half][row][72]
    __shared__ float Cx[12][1024];                   // K-half combine buffer
    const int tid = threadIdx.x;
    const int w = tid >> 6, lane = tid & 63, ln5 = lane & 31, hi = lane >> 5;
    const int s = w >> 2, wn = w & 3;
    const int tt = wn & 1, hp = wn >> 1;
    const int r0 = blockIdx.x * 64;

    float4 xr[2][2];
    auto prefetch = [&](int i) {
#pragma unroll
        for (int c = 0; c < 2; ++c) {
            int col0 = (c * 8 + i) * 64;
#pragma unroll
            for (int j = 0; j < 2; ++j) {
                int f = tid + 512 * j;
                int row = f >> 4, c4 = f & 15;
                xr[c][j] = *(const float4*)(x + (size_t)(r0 + row) * D + col0 + c4 * 4);
            }
        }
    };
    prefetch(0);

    f32x16 acc[3];
    acc[0] = zero16(); acc[1] = zero16(); acc[2] = zero16();

    for (int i = 0; i < 8; ++i) {
        __syncthreads();
#pragma unroll
        for (int c = 0; c < 2; ++c)
#pragma unroll
            for (int j = 0; j < 2; ++j) {
                int f = tid + 512 * j;
                int row = f >> 4, c4 = f & 15;
                bf16x4 v;
                v[0] = (bf16)xr[c][j].x; v[1] = (bf16)xr[c][j].y;
                v[2] = (bf16)xr[c][j].z; v[3] = (bf16)xr[c][j].w;
                *(bf16x4*)&Xs[c][row * 72 + c4 * 4] = v;
            }
        if (i < 7) prefetch(i + 1);
        __syncthreads();

        const int kbase = (s * 8 + i) * 64;
        bf16x8 fx[4];
#pragma unroll
        for (int ks = 0; ks < 4; ++ks)
            fx[ks] = *(const bf16x8*)&Xs[s][(tt * 32 + ln5) * 72 + ks * 16 + hi * 8];
        // QK: transposed (A = Wt rows h in [0,128))
#pragma unroll
        for (int j = 0; j < 2; ++j) {
            const bf16* Wr = Wt + (size_t)(hp * 64 + j * 32 + ln5) * D + kbase + hi * 8;
#pragma unroll
            for (int ks = 0; ks < 4; ++ks) {
                bf16x8 fa = *(const bf16x8*)(Wr + ks * 16);
                acc[j] = MFMA(fa, fx[ks], acc[j]);
            }
        }
        // V: direct (B = Wt rows 128 + hp*32 + ln5)
        {
            const bf16* Wr = Wt + (size_t)(128 + hp * 32 + ln5) * D + kbase + hi * 8;
#pragma unroll
            for (int ks = 0; ks < 4; ++ks) {
                bf16x8 fb = *(const bf16x8*)(Wr + ks * 16);
                acc[2] = MFMA(fx[ks], fb, acc[2]);
            }
        }
    }

    __syncthreads();                       // compute done before Cx overlay use
    if (s == 1) {
#pragma unroll
        for (int tile = 0; tile < 3; ++tile) {
            float* Cp = &Cx[wn * 3 + tile][0];
#pragma unroll
            for (int g = 0; g < 4; ++g)
#pragma unroll
                for (int k = 0; k < 4; ++k)
                    Cp[(8 * g + 4 * hi + k) * 32 + ln5] = acc[tile][4 * g + k];
        }
    }
    __syncthreads();
    if (s == 0) {
#pragma unroll
        for (int tile = 0; tile < 3; ++tile) {
            const float* Cp = &Cx[wn * 3 + tile][0];
#pragma unroll
            for (int g = 0; g < 4; ++g)
#pragma unroll
                for (int k = 0; k < 4; ++k)
                    acc[tile][4 * g + k] += Cp[(8 * g + 4 * hi + k) * 32 + ln5];
        }
        // QK store: C^T[h][t] -> Og[t][h], 4 contiguous h per bf16x4
        int t = r0 + tt * 32 + ln5;
#pragma unroll
        for (int j = 0; j < 2; ++j) {
            int htile = 2 * hp + j;                     // 0..3: Q h-tiles then K
            bf16* Og = (htile < 2) ? Qg : Kg;
            int hb = (htile & 1) * 32;
#pragma unroll
            for (int g = 0; g < 4; ++g) {
                bf16x4 vv;
#pragma unroll
                for (int k = 0; k < 4; ++k) vv[k] = (bf16)acc[j][4 * g + k];
                *(bf16x4*)(Og + (size_t)t * HS + hb + 8 * g + 4 * hi) = vv;
            }
        }
        // V store: C[t][h] -> Vtg[h][t], 4 contiguous t per bf16x4
        {
            int h = hp * 32 + ln5;
#pragma unroll
            for (int g = 0; g < 4; ++g) {
                bf16x4 vv;
#pragma unroll
                for (int k = 0; k < 4; ++k) vv[k] = (bf16)acc[2][4 * g + k];
                *(bf16x4*)(Vtg + (size_t)h * ROWS + r0 + tt * 32 + 8 * g + 4 * hi) = vv;
            }
        }
    }
}

// ---- attention: 64-q-row tile/block, k-split across blocks ----
__global__ __launch_bounds__(256, 2) void attn(
    const bf16* __restrict__ Qg, const bf16* __restrict__ Kg,
    const bf16* __restrict__ Vtg, float* __restrict__ Op,
    float* __restrict__ Lp, float* __restrict__ out, int split)
{
    __shared__ __align__(16) short Qs[64 * 72];
    __shared__ __align__(16) short Ks[2][64 * 72];
    __shared__ __align__(16) short VTs[2][64 * 72];
    __shared__ __align__(16) short Ps[4][32 * 72];

    const int tid = threadIdx.x;
    const int w = tid >> 6, lane = tid & 63, ln5 = lane & 31, hi = lane >> 5;
    const int wq = w & 1, wk = w >> 1;
    const int half = (split == 2) ? (blockIdx.x >> 8) : 0;
    const int r = blockIdx.x & 255;
    const int b = r & 3, qt = r >> 2;
    const int rbase = b * T;
    const int ns = (split == 2) ? 16 : 32;
    const int s0 = half * ns;

#pragma unroll
    for (int j = 0; j < 2; ++j) {
        int i = tid + 256 * j;
        int qr = i >> 3, c = i & 7;
        *(int4*)&Qs[qr * 72 + c * 8] =
            *(const int4*)(Qg + (size_t)(rbase + qt * 64 + qr) * HS + c * 8);
    }

    int4 kreg[2][2], vreg[2][2];
    auto preload = [&](int s) {
#pragma unroll
        for (int h = 0; h < 2; ++h)
#pragma unroll
            for (int j = 0; j < 2; ++j) {
                int i = tid + 256 * j;
                int rr = i >> 3, c = i & 7;
                kreg[h][j] = *(const int4*)(Kg + (size_t)(rbase + (h * 32 + s) * 64 + rr) * HS + c * 8);
                vreg[h][j] = *(const int4*)(Vtg + (size_t)rr * ROWS + rbase + (h * 32 + s) * 64 + c * 8);
            }
    };
    preload(s0);
    __syncthreads();

    bf16x8 bq[4];
#pragma unroll
    for (int ks = 0; ks < 4; ++ks)
        bq[ks] = *(const bf16x8*)&Qs[(wq * 32 + ln5) * 72 + ks * 16 + hi * 8];

    f32x16 O0 = zero16(), O1 = zero16();
    float l = 0.f;
    short* Pw = Ps[w];

    for (int i = 0; i < ns; ++i) {
        const int s = s0 + i;
        __syncthreads();
#pragma unroll
        for (int h = 0; h < 2; ++h)
#pragma unroll
            for (int j = 0; j < 2; ++j) {
                int ii = tid + 256 * j;
                int rr = ii >> 3, c = ii & 7;
                *(int4*)&Ks[h][rr * 72 + c * 8]  = kreg[h][j];
                *(int4*)&VTs[h][rr * 72 + c * 8] = vreg[h][j];
            }
        if (i < ns - 1) preload(s + 1);
        __syncthreads();

        f32x16 S0 = zero16(), S1 = zero16();
#pragma unroll
        for (int ks = 0; ks < 4; ++ks) {
            bf16x8 a0 = *(const bf16x8*)&Ks[wk][ln5 * 72 + ks * 16 + hi * 8];
            bf16x8 a1 = *(const bf16x8*)&Ks[wk][(32 + ln5) * 72 + ks * 16 + hi * 8];
            S0 = MFMA(a0, bq[ks], S0);
            S1 = MFMA(a1, bq[ks], S1);
        }

#pragma unroll
        for (int g = 0; g < 4; ++g) {
            float p0 = __builtin_amdgcn_exp2f(S0[4 * g + 0]);
            float p1 = __builtin_amdgcn_exp2f(S0[4 * g + 1]);
            float p2 = __builtin_amdgcn_exp2f(S0[4 * g + 2]);
            float p3 = __builtin_amdgcn_exp2f(S0[4 * g + 3]);
            l += (p0 + p1) + (p2 + p3);
            bf16x4 pv; pv[0] = (bf16)p0; pv[1] = (bf16)p1; pv[2] = (bf16)p2; pv[3] = (bf16)p3;
            *(bf16x4*)&Pw[ln5 * 72 + 8 * g + 4 * hi] = pv;
        }
#pragma unroll
        for (int g = 0; g < 4; ++g) {
            float p0 = __builtin_amdgcn_exp2f(S1[4 * g + 0]);
            float p1 = __builtin_amdgcn_exp2f(S1[4 * g + 1]);
            float p2 = __builtin_amdgcn_exp2f(S1[4 * g + 2]);
            float p3 = __builtin_amdgcn_exp2f(S1[4 * g + 3]);
            l += (p0 + p1) + (p2 + p3);
            bf16x4 pv; pv[0] = (bf16)p0; pv[1] = (bf16)p1; pv[2] = (bf16)p2; pv[3] = (bf16)p3;
            *(bf16x4*)&Pw[ln5 * 72 + 32 + 8 * g + 4 * hi] = pv;
        }

#pragma unroll
        for (int ks = 0; ks < 4; ++ks) {
            bf16x8 bp = *(const bf16x8*)&Pw[ln5 * 72 + ks * 16 + hi * 8];
            bf16x8 a0 = *(const bf16x8*)&VTs[wk][ln5 * 72 + ks * 16 + hi * 8];
            bf16x8 a1 = *(const bf16x8*)&VTs[wk][(32 + ln5) * 72 + ks * 16 + hi * 8];
            O0 = MFMA(a0, bp, O0);
            O1 = MFMA(a1, bp, O1);
        }
    }

    l += __shfl_xor(l, 32, 64);
    __syncthreads();

    float* Ox = (float*)&Ks[0][0];
    float* Lx = (float*)&VTs[0][0];
    if (wk == 1) {
#pragma unroll
        for (int rr = 0; rr < 16; ++rr) Ox[(wq * 32 + rr) * 64 + lane] = O0[rr];
#pragma unroll
        for (int rr = 0; rr < 16; ++rr) Ox[(wq * 32 + 16 + rr) * 64 + lane] = O1[rr];
        Lx[wq * 64 + lane] = l;
    }
    __syncthreads();
    if (wk == 0) {
#pragma unroll
        for (int rr = 0; rr < 16; ++rr) O0[rr] += Ox[(wq * 32 + rr) * 64 + lane];
#pragma unroll
        for (int rr = 0; rr < 16; ++rr) O1[rr] += Ox[(wq * 32 + 16 + rr) * 64 + lane];
        l += Lx[wq * 64 + lane];
        int qrow = rbase + qt * 64 + wq * 32 + ln5;
        if (split == 1) {
            float inv = 1.0f / l;
#pragma unroll
            for (int g = 0; g < 4; ++g) {
                float4 o;
                o.x = O0[4 * g + 0] * inv; o.y = O0[4 * g + 1] * inv;
                o.z = O0[4 * g + 2] * inv; o.w = O0[4 * g + 3] * inv;
                *(float4*)(out + (size_t)qrow * HS + 8 * g + 4 * hi) = o;
            }
#pragma unroll
            for (int g = 0; g < 4; ++g) {
                float4 o;
                o.x = O1[4 * g + 0] * inv; o.y = O1[4 * g + 1] * inv;
                o.z = O1[4 * g + 2] * inv; o.w = O1[4 * g + 3] * inv;
                *(float4*)(out + (size_t)qrow * HS + 32 + 8 * g + 4 * hi) = o;
            }
        } else {
            float* Od = Op + (size_t)half * ROWS * HS + (size_t)qrow * HS;
#pragma unroll
            for (int g = 0; g < 4; ++g) {
                float4 o;
                o.x = O0[4 * g + 0]; o.y = O0[4 * g + 1];
                o.z = O0[4 * g + 2]; o.w = O0[4 * g + 3];
                *(float4*)(Od + 8 * g + 4 * hi) = o;
            }
#pragma unroll
            for (int g = 0; g < 4; ++g) {
                float4 o;
                o.x = O1[4 * g + 0]; o.y = O1[4 * g + 1];
                o.z = O1[4 * g + 2]; o.w = O1[4 * g + 3];
                *(float4*)(Od + 32 + 8 * g + 4 * hi) = o;
            }
            if (hi == 0) Lp[half * ROWS + qrow] = l;
        }
    }
}

// ---- reduce: out = (O0 + O1) / (l0 + l1) ----
__global__ __launch_bounds__(256) void attn_reduce(
    const float* __restrict__ Op, const float* __restrict__ Lp,
    float* __restrict__ out)
{
    int idx = blockIdx.x * 256 + threadIdx.x;        // float4 index
    int row = idx >> 4;
    float4 a = *(const float4*)(Op + (size_t)idx * 4);
    float4 b = *(const float4*)(Op + (size_t)ROWS * HS + (size_t)idx * 4);
    float inv = 1.0f / (Lp[row] + Lp[ROWS + row]);
    float4 o;
    o.x = (a.x + b.x) * inv; o.y = (a.y + b.y) * inv;
    o.z = (a.z + b.z) * inv; o.w = (a.w + b.w) * inv;
    *(float4*)(out + (size_t)idx * 4) = o;
}

extern "C" void kernel_launch(void* const* d_in, const int* in_sizes, int n_in,
                              void* d_out, int out_size, void* d_ws, size_t ws_size,
                              hipStream_t stream)
{
    const float* x  = (const float*)d_in[0];
    const float* Wq = (const float*)d_in[1];
    const float* Wk = (const float*)d_in[2];
    const float* Wv = (const float*)d_in[3];
    float* out = (float*)d_out;

    char* ws = (char*)d_ws;
    bf16* Qg  = (bf16*)(ws);                          // 2 MB  [16384][64]
    bf16* Kg  = (bf16*)(ws + ((size_t)2 << 20));      // 2 MB  [16384][64]
    bf16* Vtg = (bf16*)(ws + ((size_t)4 << 20));      // 2 MB  [64][16384]
    bf16* Wt  = (bf16*)(ws + ((size_t)6 << 20));      // 384 KB [192][1024]
    // Lp overlays Wt (dead after proj); Op fresh at 6.5 MB (2 x 4 MB)
    float* Lp = (float*)(ws + ((size_t)6 << 20));
    float* Op = (float*)(ws + ((size_t)6 << 20) + ((size_t)1 << 19));

    size_t need = ((size_t)6 << 20) + ((size_t)1 << 19)
                + (size_t)2 * ROWS * HS * sizeof(float);
    int split = (ws_size >= need) ? 2 : 1;

    prep_wt<<<48, 256, 0, stream>>>(Wq, Wk, Wv, Wt);
    qkv_proj<<<ROWS / 64, 512, 0, stream>>>(x, Wt, Qg, Kg, Vtg);
    attn<<<256 * split, 256, 0, stream>>>(Qg, Kg, Vtg, Op, Lp, out, split);
    if (split == 2)
        attn_reduce<<<(ROWS * HS / 4) / 256, 256, 0, stream>>>(Op, Lp, out);
}